// Round 1
// baseline (394.890 us; speedup 1.0000x reference)
//
#include <hip/hip_runtime.h>
#include <hip/hip_bf16.h>
#include <stdint.h>

// Problem constants (fixed by the reference): x[4,2048,4096] f32, qweight[4096,4096] i32,
// scale/zp scalars f32, bias[4096] f32. out[4,2048,4096] f32.
#define M_DIM 8192
#define N_DIM 4096
#define K_DIM 4096

typedef __attribute__((ext_vector_type(8))) __bf16 bf16x8;
typedef __attribute__((ext_vector_type(4))) float f32x4;
typedef __attribute__((ext_vector_type(8))) unsigned short ushort8;

__device__ __forceinline__ unsigned short f2bf(float f) {
  union { float f; uint32_t u; } v; v.f = f;
  uint32_t u = v.u;
  return (unsigned short)((u + 0x7FFFu + ((u >> 16) & 1u)) >> 16);  // RNE
}

__device__ __forceinline__ void gload_lds16(const void* g, void* l) {
  __builtin_amdgcn_global_load_lds((const __attribute__((address_space(1))) void*)g,
                                   (__attribute__((address_space(3))) void*)l,
                                   16, 0, 0);
}

// ---- prepack kernels ----
__global__ void cvt_x_kernel(const float* __restrict__ x, unsigned short* __restrict__ xb,
                             long long n8) {
  long long i = (long long)blockIdx.x * blockDim.x + threadIdx.x;
  long long stride = (long long)gridDim.x * blockDim.x;
  for (; i < n8; i += stride) {
    const float4* p = (const float4*)x + i * 2;
    float4 a = p[0], b = p[1];
    ushort8 u;
    u[0] = f2bf(a.x); u[1] = f2bf(a.y); u[2] = f2bf(a.z); u[3] = f2bf(a.w);
    u[4] = f2bf(b.x); u[5] = f2bf(b.y); u[6] = f2bf(b.z); u[7] = f2bf(b.w);
    *(ushort8*)(xb + i * 8) = u;
  }
}

__global__ void dequant_w_kernel(const int* __restrict__ q, const float* __restrict__ scale,
                                 const float* __restrict__ zp, unsigned short* __restrict__ wb,
                                 long long n8) {
  float s = scale[0], z = zp[0];
  long long i = (long long)blockIdx.x * blockDim.x + threadIdx.x;
  long long stride = (long long)gridDim.x * blockDim.x;
  for (; i < n8; i += stride) {
    const int4* p = (const int4*)q + i * 2;
    int4 a = p[0], b = p[1];
    ushort8 u;
    u[0] = f2bf(s * ((float)a.x - z)); u[1] = f2bf(s * ((float)a.y - z));
    u[2] = f2bf(s * ((float)a.z - z)); u[3] = f2bf(s * ((float)a.w - z));
    u[4] = f2bf(s * ((float)b.x - z)); u[5] = f2bf(s * ((float)b.y - z));
    u[6] = f2bf(s * ((float)b.z - z)); u[7] = f2bf(s * ((float)b.w - z));
    *(ushort8*)(wb + i * 8) = u;
  }
}

// ---- GEMM: out[m][n] = sum_k A[m][k]*W[n][k] + bias[n] ----
// 128x128 tile, BK=32, 4 waves (2x2), each wave 64x64 = 4x4 frags of 16x16.
template <bool PRE>
__global__ __launch_bounds__(256) void gemm_kernel(
    const unsigned short* __restrict__ xb, const unsigned short* __restrict__ wb,
    const float* __restrict__ x, const int* __restrict__ qw,
    const float* __restrict__ scale, const float* __restrict__ zp,
    const float* __restrict__ bias, float* __restrict__ out) {
  __shared__ unsigned short lds_a[128 * 32];
  __shared__ unsigned short lds_b[128 * 32];

  const int t = threadIdx.x;
  const int lane = t & 63;
  const int wid = t >> 6;
  const int wr = wid >> 1, wc = wid & 1;
  const int fr = lane & 15, fq = lane >> 4;

  // XCD-aware swizzle: grid = 2048 (divisible by 8)
  const int nwg = gridDim.x;
  const int cpx = nwg >> 3;
  const int bid = blockIdx.x;
  const int swz = (bid & 7) * cpx + (bid >> 3);
  const int bx = swz & 31;   // N/128 = 32
  const int by = swz >> 5;   // M/128 = 64
  const int brow = by * 128, bcol = bx * 128;

  const int r0 = t >> 2;          // 0..63
  const int c8 = (t & 3) * 8;     // 0,8,16,24

  f32x4 acc[4][4] = {};

  float ss = 0.f, zs = 0.f;
  if constexpr (!PRE) { ss = scale[0]; zs = zp[0]; }

  for (int kk = 0; kk < K_DIM; kk += 32) {
    if constexpr (PRE) {
      __syncthreads();  // previous compute done before LDS overwrite
      #pragma unroll
      for (int i = 0; i < 2; ++i) {
        gload_lds16(xb + (size_t)(brow + i * 64 + r0) * K_DIM + kk + c8,
                    lds_a + ((size_t)i * 256 + t) * 8);
        gload_lds16(wb + (size_t)(bcol + i * 64 + r0) * K_DIM + kk + c8,
                    lds_b + ((size_t)i * 256 + t) * 8);
      }
      __syncthreads();  // drains vmcnt -> tiles visible
    } else {
      ushort8 ua[2], ub[2];
      #pragma unroll
      for (int i = 0; i < 2; ++i) {
        const float* gp = x + (size_t)(brow + i * 64 + r0) * K_DIM + kk + c8;
        float4 v0 = *(const float4*)gp;
        float4 v1 = *(const float4*)(gp + 4);
        ua[i][0] = f2bf(v0.x); ua[i][1] = f2bf(v0.y); ua[i][2] = f2bf(v0.z); ua[i][3] = f2bf(v0.w);
        ua[i][4] = f2bf(v1.x); ua[i][5] = f2bf(v1.y); ua[i][6] = f2bf(v1.z); ua[i][7] = f2bf(v1.w);
        const int* qp = qw + (size_t)(bcol + i * 64 + r0) * K_DIM + kk + c8;
        int4 q0 = *(const int4*)qp;
        int4 q1 = *(const int4*)(qp + 4);
        ub[i][0] = f2bf(ss * ((float)q0.x - zs)); ub[i][1] = f2bf(ss * ((float)q0.y - zs));
        ub[i][2] = f2bf(ss * ((float)q0.z - zs)); ub[i][3] = f2bf(ss * ((float)q0.w - zs));
        ub[i][4] = f2bf(ss * ((float)q1.x - zs)); ub[i][5] = f2bf(ss * ((float)q1.y - zs));
        ub[i][6] = f2bf(ss * ((float)q1.z - zs)); ub[i][7] = f2bf(ss * ((float)q1.w - zs));
      }
      __syncthreads();  // previous compute done
      #pragma unroll
      for (int i = 0; i < 2; ++i) {
        *(ushort8*)(lds_a + ((size_t)i * 256 + t) * 8) = ua[i];
        *(ushort8*)(lds_b + ((size_t)i * 256 + t) * 8) = ub[i];
      }
      __syncthreads();  // writes visible
    }

    bf16x8 af[4], bfr[4];
    #pragma unroll
    for (int m = 0; m < 4; ++m)
      af[m] = *(const bf16x8*)(lds_a + (wr * 64 + m * 16 + fr) * 32 + fq * 8);
    #pragma unroll
    for (int n = 0; n < 4; ++n)
      bfr[n] = *(const bf16x8*)(lds_b + (wc * 64 + n * 16 + fr) * 32 + fq * 8);
    #pragma unroll
    for (int m = 0; m < 4; ++m)
      #pragma unroll
      for (int n = 0; n < 4; ++n)
        acc[m][n] = __builtin_amdgcn_mfma_f32_16x16x32_bf16(af[m], bfr[n], acc[m][n], 0, 0, 0);
  }

  // epilogue: C/D layout col = lane&15, row = (lane>>4)*4 + j  [verified m89/m91]
  #pragma unroll
  for (int n = 0; n < 4; ++n) {
    const int col = bcol + wc * 64 + n * 16 + fr;
    const float bv = bias[col];
    #pragma unroll
    for (int m = 0; m < 4; ++m) {
      const int rowb = brow + wr * 64 + m * 16 + fq * 4;
      #pragma unroll
      for (int j = 0; j < 4; ++j)
        out[(size_t)(rowb + j) * N_DIM + col] = acc[m][n][j] + bv;
    }
  }
}

extern "C" void kernel_launch(void* const* d_in, const int* in_sizes, int n_in,
                              void* d_out, int out_size, void* d_ws, size_t ws_size,
                              hipStream_t stream) {
  const float* x = (const float*)d_in[0];
  const int* qw = (const int*)d_in[1];
  const float* scale = (const float*)d_in[2];
  const float* zp = (const float*)d_in[3];
  const float* bias = (const float*)d_in[4];
  float* out = (float*)d_out;

  const size_t xb_bytes = (size_t)M_DIM * K_DIM * 2;
  const size_t wb_bytes = (size_t)N_DIM * K_DIM * 2;
  const bool pre = ws_size >= xb_bytes + wb_bytes;

  const int grid = (M_DIM / 128) * (N_DIM / 128);  // 2048, divisible by 8

  if (pre) {
    unsigned short* xb = (unsigned short*)d_ws;
    unsigned short* wb = (unsigned short*)((char*)d_ws + xb_bytes);
    cvt_x_kernel<<<2048, 256, 0, stream>>>(x, xb, (long long)M_DIM * K_DIM / 8);
    dequant_w_kernel<<<2048, 256, 0, stream>>>(qw, scale, zp, wb, (long long)N_DIM * K_DIM / 8);
    gemm_kernel<true><<<grid, 256, 0, stream>>>(xb, wb, nullptr, nullptr, nullptr, nullptr, bias, out);
  } else {
    gemm_kernel<false><<<grid, 256, 0, stream>>>(nullptr, nullptr, x, qw, scale, zp, bias, out);
  }
}

// Round 2
// 315.878 us; speedup vs baseline: 1.2501x; 1.2501x over previous
//
#include <hip/hip_runtime.h>
#include <hip/hip_bf16.h>
#include <stdint.h>

// x[4,2048,4096] f32, qweight[4096,4096] i32, scale/zp f32 scalars, bias[4096] f32
// out = x @ (scale*(q-zp))^T + bias : M=8192, N=4096, K=4096, f32 out.
#define M_DIM 8192
#define N_DIM 4096
#define K_DIM 4096

typedef __attribute__((ext_vector_type(8))) __bf16 bf16x8;
typedef __attribute__((ext_vector_type(4))) float f32x4;
typedef __attribute__((ext_vector_type(8))) unsigned short ushort8;

__device__ __forceinline__ unsigned short f2bf(float f) {
  union { float f; uint32_t u; } v; v.f = f;
  uint32_t u = v.u;
  return (unsigned short)((u + 0x7FFFu + ((u >> 16) & 1u)) >> 16);  // RNE
}

__device__ __forceinline__ void gload_lds16(const void* g, void* l) {
  __builtin_amdgcn_global_load_lds((const __attribute__((address_space(1))) void*)g,
                                   (__attribute__((address_space(3))) void*)l,
                                   16, 0, 0);
}

#define RAW_BAR() asm volatile("s_barrier" ::: "memory")
#define VMW(n) asm volatile("s_waitcnt vmcnt(" #n ")" ::: "memory")

// ---- prepack kernels ----
__global__ void cvt_x_kernel(const float* __restrict__ x, unsigned short* __restrict__ xb,
                             long long n8) {
  long long i = (long long)blockIdx.x * blockDim.x + threadIdx.x;
  long long stride = (long long)gridDim.x * blockDim.x;
  for (; i < n8; i += stride) {
    const float4* p = (const float4*)x + i * 2;
    float4 a = p[0], b = p[1];
    ushort8 u;
    u[0] = f2bf(a.x); u[1] = f2bf(a.y); u[2] = f2bf(a.z); u[3] = f2bf(a.w);
    u[4] = f2bf(b.x); u[5] = f2bf(b.y); u[6] = f2bf(b.z); u[7] = f2bf(b.w);
    *(ushort8*)(xb + i * 8) = u;
  }
}

__global__ void dequant_w_kernel(const int* __restrict__ q, const float* __restrict__ scale,
                                 const float* __restrict__ zp, unsigned short* __restrict__ wb,
                                 long long n8) {
  float s = scale[0], z = zp[0];
  long long i = (long long)blockIdx.x * blockDim.x + threadIdx.x;
  long long stride = (long long)gridDim.x * blockDim.x;
  for (; i < n8; i += stride) {
    const int4* p = (const int4*)q + i * 2;
    int4 a = p[0], b = p[1];
    ushort8 u;
    u[0] = f2bf(s * ((float)a.x - z)); u[1] = f2bf(s * ((float)a.y - z));
    u[2] = f2bf(s * ((float)a.z - z)); u[3] = f2bf(s * ((float)a.w - z));
    u[4] = f2bf(s * ((float)b.x - z)); u[5] = f2bf(s * ((float)b.y - z));
    u[6] = f2bf(s * ((float)b.z - z)); u[7] = f2bf(s * ((float)b.w - z));
    *(ushort8*)(wb + i * 8) = u;
  }
}

// ---- main GEMM: 256x256 tile, BK=32, 8 waves (2Mx4N), 4-deep LDS ring,
// counted vmcnt (T4), XOR granule swizzle (T2), raw barriers, setprio (T5).
// Per wave: 128x64 output = 8x4 frags of 16x16, acc = 128 VGPRs.
// LDS buffer: A[256][32] + B[256][32] bf16 = 32 KiB; ring of 4 = 128 KiB.
#define BK 32
#define NT (K_DIM / BK)          // 128
#define BUF_SHORTS 16384          // per ring slot (A 8192 + B 8192 shorts)

__global__ __launch_bounds__(512, 2) void gemm256_kernel(
    const unsigned short* __restrict__ xb, const unsigned short* __restrict__ wb,
    const float* __restrict__ bias, float* __restrict__ out) {
  __shared__ unsigned short lds[4 * BUF_SHORTS];  // 128 KiB

  const int t = threadIdx.x;
  const int lane = t & 63;
  const int wid = t >> 6;          // 0..7
  const int wr = wid >> 2;         // 0..1  (M half)
  const int wc = wid & 3;          // 0..3  (N quarter)
  const int fr = lane & 15, fq = lane >> 4;

  // XCD-aware bijective swizzle; grid = 512 (divisible by 8)
  const int bid = blockIdx.x;
  const int swz = ((bid & 7) << 6) | (bid >> 3);
  const int bx = swz & 15;         // N/256 = 16
  const int by = swz >> 4;         // M/256 = 32
  const int brow = by * 256, bcol = bx * 256;

  // staging geometry: per tile, A = 256x32 bf16 = 16 KiB = 512 thr x 2 loads x 16B.
  // linear LDS dest (gload_lds: wave-uniform base + lane*16B), source granule
  // pre-swizzled: gG = (t&3) ^ ((t>>3)&3)  [involution, matches read-side XOR]
  const int r2 = t >> 2;                        // base row (load 0); load 1: +128
  const int gG = (t & 3) ^ ((t >> 3) & 3);
  const unsigned short* gA = xb + (size_t)(brow + r2) * K_DIM + gG * 8;
  const unsigned short* gB = wb + (size_t)(bcol + r2) * K_DIM + gG * 8;

  // read-side swizzled granule: row = ...+fr, swz sel = (row>>1)&3 = (fr>>1)&3
  const int gsel = (fq ^ ((fr >> 1) & 3)) * 8;

  f32x4 acc[8][4] = {};

  #define STAGE(tile)                                                          \
    do {                                                                       \
      unsigned short* la_ = lds + ((tile) & 3) * BUF_SHORTS + t * 8;           \
      unsigned short* lb_ = la_ + 8192;                                        \
      const unsigned short* a_ = gA + (tile) * BK;                             \
      const unsigned short* b_ = gB + (tile) * BK;                             \
      gload_lds16(a_, la_);                                                    \
      gload_lds16(a_ + (size_t)128 * K_DIM, la_ + 4096);                       \
      gload_lds16(b_, lb_);                                                    \
      gload_lds16(b_ + (size_t)128 * K_DIM, lb_ + 4096);                       \
    } while (0)

  #define COMPUTE(tile)                                                        \
    do {                                                                       \
      const unsigned short* la_ = lds + ((tile) & 3) * BUF_SHORTS;             \
      const unsigned short* lb_ = la_ + 8192;                                  \
      bf16x8 af[8], bf[4];                                                     \
      _Pragma("unroll")                                                        \
      for (int m = 0; m < 8; ++m)                                              \
        af[m] = *(const bf16x8*)(la_ + (wr * 128 + m * 16 + fr) * 32 + gsel);  \
      _Pragma("unroll")                                                        \
      for (int n = 0; n < 4; ++n)                                              \
        bf[n] = *(const bf16x8*)(lb_ + (wc * 64 + n * 16 + fr) * 32 + gsel);   \
      __builtin_amdgcn_s_setprio(1);                                           \
      _Pragma("unroll")                                                        \
      for (int m = 0; m < 8; ++m) {                                            \
        _Pragma("unroll")                                                      \
        for (int n = 0; n < 4; ++n)                                            \
          acc[m][n] = __builtin_amdgcn_mfma_f32_16x16x32_bf16(af[m], bf[n],    \
                                                              acc[m][n], 0, 0, 0); \
      }                                                                        \
      __builtin_amdgcn_s_setprio(0);                                           \
    } while (0)

  // prologue: 3 tiles in flight
  STAGE(0); STAGE(1); STAGE(2);

  // steady state: stage t+3, wait own tile-t loads (12 = 3 tiles x 4 loads stay
  // in flight), barrier (all waves' t retired), compute, barrier (reads done ->
  // next iter may overwrite ring slot (t+4)&3 == t&3... staged two iters later).
  for (int tt = 0; tt < NT - 3; ++tt) {
    STAGE(tt + 3);
    VMW(12);
    RAW_BAR();
    COMPUTE(tt);
    RAW_BAR();
  }
  VMW(8);  RAW_BAR(); COMPUTE(NT - 3); RAW_BAR();
  VMW(4);  RAW_BAR(); COMPUTE(NT - 2); RAW_BAR();
  VMW(0);  RAW_BAR(); COMPUTE(NT - 1);

  #undef STAGE
  #undef COMPUTE

  // epilogue: C/D layout col = lane&15, row = (lane>>4)*4 + j
  #pragma unroll
  for (int n = 0; n < 4; ++n) {
    const int col = bcol + wc * 64 + n * 16 + fr;
    const float bv = bias[col];
    #pragma unroll
    for (int m = 0; m < 8; ++m) {
      const int rowb = brow + wr * 128 + m * 16 + fq * 4;
      #pragma unroll
      for (int j = 0; j < 4; ++j)
        out[(size_t)(rowb + j) * N_DIM + col] = acc[m][n][j] + bv;
    }
  }
}

// ---- fallback (ws too small): fused dequant 128^2 tile, correct but slower ----
__global__ __launch_bounds__(256) void gemm_fallback_kernel(
    const float* __restrict__ x, const int* __restrict__ qw,
    const float* __restrict__ scale, const float* __restrict__ zp,
    const float* __restrict__ bias, float* __restrict__ out) {
  __shared__ unsigned short lds_a[128 * 32];
  __shared__ unsigned short lds_b[128 * 32];
  const int t = threadIdx.x;
  const int lane = t & 63;
  const int wid = t >> 6;
  const int wr = wid >> 1, wc = wid & 1;
  const int fr = lane & 15, fq = lane >> 4;
  const int nwg = gridDim.x;
  const int cpx = nwg >> 3;
  const int bid = blockIdx.x;
  const int swz = (bid & 7) * cpx + (bid >> 3);
  const int bx = swz & 31, by = swz >> 5;
  const int brow = by * 128, bcol = bx * 128;
  const int r0 = t >> 2, c8 = (t & 3) * 8;
  f32x4 acc[4][4] = {};
  const float ss = scale[0], zs = zp[0];
  for (int kk = 0; kk < K_DIM; kk += 32) {
    ushort8 ua[2], ub[2];
    #pragma unroll
    for (int i = 0; i < 2; ++i) {
      const float* gp = x + (size_t)(brow + i * 64 + r0) * K_DIM + kk + c8;
      float4 v0 = *(const float4*)gp;
      float4 v1 = *(const float4*)(gp + 4);
      ua[i][0] = f2bf(v0.x); ua[i][1] = f2bf(v0.y); ua[i][2] = f2bf(v0.z); ua[i][3] = f2bf(v0.w);
      ua[i][4] = f2bf(v1.x); ua[i][5] = f2bf(v1.y); ua[i][6] = f2bf(v1.z); ua[i][7] = f2bf(v1.w);
      const int* qp = qw + (size_t)(bcol + i * 64 + r0) * K_DIM + kk + c8;
      int4 q0 = *(const int4*)qp;
      int4 q1 = *(const int4*)(qp + 4);
      ub[i][0] = f2bf(ss * ((float)q0.x - zs)); ub[i][1] = f2bf(ss * ((float)q0.y - zs));
      ub[i][2] = f2bf(ss * ((float)q0.z - zs)); ub[i][3] = f2bf(ss * ((float)q0.w - zs));
      ub[i][4] = f2bf(ss * ((float)q1.x - zs)); ub[i][5] = f2bf(ss * ((float)q1.y - zs));
      ub[i][6] = f2bf(ss * ((float)q1.z - zs)); ub[i][7] = f2bf(ss * ((float)q1.w - zs));
    }
    __syncthreads();
    #pragma unroll
    for (int i = 0; i < 2; ++i) {
      *(ushort8*)(lds_a + ((size_t)i * 256 + t) * 8) = ua[i];
      *(ushort8*)(lds_b + ((size_t)i * 256 + t) * 8) = ub[i];
    }
    __syncthreads();
    bf16x8 af[4], bfr[4];
    #pragma unroll
    for (int m = 0; m < 4; ++m)
      af[m] = *(const bf16x8*)(lds_a + (wr * 64 + m * 16 + fr) * 32 + fq * 8);
    #pragma unroll
    for (int n = 0; n < 4; ++n)
      bfr[n] = *(const bf16x8*)(lds_b + (wc * 64 + n * 16 + fr) * 32 + fq * 8);
    #pragma unroll
    for (int m = 0; m < 4; ++m)
      #pragma unroll
      for (int n = 0; n < 4; ++n)
        acc[m][n] = __builtin_amdgcn_mfma_f32_16x16x32_bf16(af[m], bfr[n], acc[m][n], 0, 0, 0);
  }
  #pragma unroll
  for (int n = 0; n < 4; ++n) {
    const int col = bcol + wc * 64 + n * 16 + fr;
    const float bv = bias[col];
    #pragma unroll
    for (int m = 0; m < 4; ++m) {
      const int rowb = brow + wr * 64 + m * 16 + fq * 4;
      #pragma unroll
      for (int j = 0; j < 4; ++j)
        out[(size_t)(rowb + j) * N_DIM + col] = acc[m][n][j] + bv;
    }
  }
}

extern "C" void kernel_launch(void* const* d_in, const int* in_sizes, int n_in,
                              void* d_out, int out_size, void* d_ws, size_t ws_size,
                              hipStream_t stream) {
  const float* x = (const float*)d_in[0];
  const int* qw = (const int*)d_in[1];
  const float* scale = (const float*)d_in[2];
  const float* zp = (const float*)d_in[3];
  const float* bias = (const float*)d_in[4];
  float* out = (float*)d_out;

  const size_t xb_bytes = (size_t)M_DIM * K_DIM * 2;
  const size_t wb_bytes = (size_t)N_DIM * K_DIM * 2;

  if (ws_size >= xb_bytes + wb_bytes) {
    unsigned short* xbuf = (unsigned short*)d_ws;
    unsigned short* wbuf = (unsigned short*)((char*)d_ws + xb_bytes);
    cvt_x_kernel<<<2048, 256, 0, stream>>>(x, xbuf, (long long)M_DIM * K_DIM / 8);
    dequant_w_kernel<<<2048, 256, 0, stream>>>(qw, scale, zp, wbuf, (long long)N_DIM * K_DIM / 8);
    const int grid = (M_DIM / 256) * (N_DIM / 256);  // 512, divisible by 8
    gemm256_kernel<<<grid, 512, 0, stream>>>(xbuf, wbuf, bias, out);
  } else {
    const int grid = (M_DIM / 128) * (N_DIM / 128);  // 2048
    gemm_fallback_kernel<<<grid, 256, 0, stream>>>(x, qw, scale, zp, bias, out);
  }
}

// Round 3
// 305.419 us; speedup vs baseline: 1.2929x; 1.0342x over previous
//
#include <hip/hip_runtime.h>
#include <hip/hip_bf16.h>
#include <stdint.h>

// x[4,2048,4096] f32, qweight[4096,4096] i32, scale/zp f32 scalars, bias[4096] f32
// out = x @ (scale*(q-zp))^T + bias : M=8192, N=4096, K=4096, f32 out.
#define M_DIM 8192
#define N_DIM 4096
#define K_DIM 4096

typedef __attribute__((ext_vector_type(8))) __bf16 bf16x8;
typedef __attribute__((ext_vector_type(4))) float f32x4;
typedef __attribute__((ext_vector_type(8))) unsigned short ushort8;

__device__ __forceinline__ unsigned short f2bf(float f) {
  union { float f; uint32_t u; } v; v.f = f;
  uint32_t u = v.u;
  return (unsigned short)((u + 0x7FFFu + ((u >> 16) & 1u)) >> 16);  // RNE
}

__device__ __forceinline__ void gload_lds16(const void* g, void* l) {
  __builtin_amdgcn_global_load_lds((const __attribute__((address_space(1))) void*)g,
                                   (__attribute__((address_space(3))) void*)l,
                                   16, 0, 0);
}

#define RAW_BAR() asm volatile("s_barrier" ::: "memory")
#define VMW(n) asm volatile("s_waitcnt vmcnt(" #n ")" ::: "memory")
#define LGKM0()                                      \
  do {                                               \
    asm volatile("s_waitcnt lgkmcnt(0)" ::: "memory"); \
    __builtin_amdgcn_sched_barrier(0);               \
  } while (0)
#define NOOP do {} while (0)

// ---- prepack kernels ----
__global__ void cvt_x_kernel(const float* __restrict__ x, unsigned short* __restrict__ xb,
                             long long n8) {
  long long i = (long long)blockIdx.x * blockDim.x + threadIdx.x;
  long long stride = (long long)gridDim.x * blockDim.x;
  for (; i < n8; i += stride) {
    const float4* p = (const float4*)x + i * 2;
    float4 a = p[0], b = p[1];
    ushort8 u;
    u[0] = f2bf(a.x); u[1] = f2bf(a.y); u[2] = f2bf(a.z); u[3] = f2bf(a.w);
    u[4] = f2bf(b.x); u[5] = f2bf(b.y); u[6] = f2bf(b.z); u[7] = f2bf(b.w);
    *(ushort8*)(xb + i * 8) = u;
  }
}

__global__ void dequant_w_kernel(const int* __restrict__ q, const float* __restrict__ scale,
                                 const float* __restrict__ zp, unsigned short* __restrict__ wb,
                                 long long n8) {
  float s = scale[0], z = zp[0];
  long long i = (long long)blockIdx.x * blockDim.x + threadIdx.x;
  long long stride = (long long)gridDim.x * blockDim.x;
  for (; i < n8; i += stride) {
    const int4* p = (const int4*)q + i * 2;
    int4 a = p[0], b = p[1];
    ushort8 u;
    u[0] = f2bf(s * ((float)a.x - z)); u[1] = f2bf(s * ((float)a.y - z));
    u[2] = f2bf(s * ((float)a.z - z)); u[3] = f2bf(s * ((float)a.w - z));
    u[4] = f2bf(s * ((float)b.x - z)); u[5] = f2bf(s * ((float)b.y - z));
    u[6] = f2bf(s * ((float)b.z - z)); u[7] = f2bf(s * ((float)b.w - z));
    *(ushort8*)(wb + i * 8) = u;
  }
}

// ---- main GEMM: 256x256 tile, BK=32, 8 waves (2Mx4N), 4-deep LDS ring,
// 2 phases per K-tile (T3), counted vmcnt never 0 in main loop (T4),
// XOR granule swizzle both-sides (T2), raw barriers, setprio around MFMA (T5).
// Per wave: 128x64 output = 8x4 frags of 16x16.
#define BK 32
#define NT (K_DIM / BK)           // 128
#define BUF_SHORTS 16384          // per ring slot (A 8192 + B 8192 shorts)

__global__ __launch_bounds__(512, 2) void gemm256_kernel(
    const unsigned short* __restrict__ xb, const unsigned short* __restrict__ wb,
    const float* __restrict__ bias, float* __restrict__ out) {
  __shared__ unsigned short lds[4 * BUF_SHORTS];  // 128 KiB

  const int t = threadIdx.x;
  const int lane = t & 63;
  const int wid = t >> 6;          // 0..7
  const int wr = wid >> 2;         // 0..1  (M half)
  const int wc = wid & 3;          // 0..3  (N quarter)
  const int fr = lane & 15, fq = lane >> 4;

  // XCD-aware bijective swizzle; grid = 512 (divisible by 8)
  const int bid = blockIdx.x;
  const int swz = ((bid & 7) << 6) | (bid >> 3);
  const int bx = swz & 15;         // N/256 = 16
  const int by = swz >> 4;         // M/256 = 32
  const int brow = by * 256, bcol = bx * 256;

  // staging: per tile, A = 256x32 bf16 = 16 KiB = 512 thr x 2 loads x 16B.
  // linear LDS dest; source granule pre-swizzled (involution matches read XOR).
  const int r2 = t >> 2;
  const int gG = (t & 3) ^ ((t >> 3) & 3);
  const unsigned short* gA = xb + (size_t)(brow + r2) * K_DIM + gG * 8;
  const unsigned short* gB = wb + (size_t)(bcol + r2) * K_DIM + gG * 8;

  // read-side swizzled granule: row bits -> (fr>>1)&3
  const int gsel = (fq ^ ((fr >> 1) & 3)) * 8;

  bf16x8 af[8], bfv[4];
  f32x4 acc[8][4] = {};

  #define STAGE_A(tile)                                                        \
    do {                                                                       \
      unsigned short* l_ = lds + ((tile) & 3) * BUF_SHORTS + t * 8;            \
      const unsigned short* g_ = gA + (size_t)(tile) * BK;                     \
      gload_lds16(g_, l_);                                                     \
      gload_lds16(g_ + (size_t)128 * K_DIM, l_ + 4096);                        \
    } while (0)

  #define STAGE_B(tile)                                                        \
    do {                                                                       \
      unsigned short* l_ = lds + ((tile) & 3) * BUF_SHORTS + 8192 + t * 8;     \
      const unsigned short* g_ = gB + (size_t)(tile) * BK;                     \
      gload_lds16(g_, l_);                                                     \
      gload_lds16(g_ + (size_t)128 * K_DIM, l_ + 4096);                        \
    } while (0)

  // Phase A: reads af[0..3] + bfv[0..3] (8 x ds_read_b128), computes m=0..3.
  #define PH_A(tile, STG)                                                      \
    do {                                                                       \
      const unsigned short* la_ = lds + ((tile) & 3) * BUF_SHORTS;             \
      const unsigned short* lb_ = la_ + 8192;                                  \
      _Pragma("unroll")                                                        \
      for (int m = 0; m < 4; ++m)                                              \
        af[m] = *(const bf16x8*)(la_ + (wr * 128 + m * 16 + fr) * 32 + gsel);  \
      _Pragma("unroll")                                                        \
      for (int n = 0; n < 4; ++n)                                              \
        bfv[n] = *(const bf16x8*)(lb_ + (wc * 64 + n * 16 + fr) * 32 + gsel);  \
      STG;                                                                     \
      RAW_BAR();                                                               \
      LGKM0();                                                                 \
      __builtin_amdgcn_s_setprio(1);                                           \
      _Pragma("unroll")                                                        \
      for (int m = 0; m < 4; ++m) {                                            \
        _Pragma("unroll")                                                      \
        for (int n = 0; n < 4; ++n)                                            \
          acc[m][n] = __builtin_amdgcn_mfma_f32_16x16x32_bf16(af[m], bfv[n],   \
                                                              acc[m][n], 0, 0, 0); \
      }                                                                        \
      __builtin_amdgcn_s_setprio(0);                                           \
      RAW_BAR();                                                               \
    } while (0)

  // Phase B: reads af[4..7] (4 x ds_read_b128), computes m=4..7. WT = vmcnt.
  #define PH_B(tile, STG, WT)                                                  \
    do {                                                                       \
      const unsigned short* la_ = lds + ((tile) & 3) * BUF_SHORTS;             \
      _Pragma("unroll")                                                        \
      for (int m = 0; m < 4; ++m)                                              \
        af[4 + m] = *(const bf16x8*)(la_ + (wr * 128 + (4 + m) * 16 + fr) * 32 + gsel); \
      STG;                                                                     \
      WT;                                                                      \
      RAW_BAR();                                                               \
      LGKM0();                                                                 \
      __builtin_amdgcn_s_setprio(1);                                           \
      _Pragma("unroll")                                                        \
      for (int m = 0; m < 4; ++m) {                                            \
        _Pragma("unroll")                                                      \
        for (int n = 0; n < 4; ++n)                                            \
          acc[4 + m][n] = __builtin_amdgcn_mfma_f32_16x16x32_bf16(af[4 + m], bfv[n], \
                                                                  acc[4 + m][n], 0, 0, 0); \
      }                                                                        \
      __builtin_amdgcn_s_setprio(0);                                           \
      RAW_BAR();                                                               \
    } while (0)

  // prologue: 3 tiles (12 loads) in flight; retire tile 0 (VMW leaves 8).
  STAGE_A(0); STAGE_B(0);
  STAGE_A(1); STAGE_B(1);
  STAGE_A(2); STAGE_B(2);
  VMW(8);
  RAW_BAR();

  // steady state: VMW(8) at iter tt retires tile tt+1 (needed next iter);
  // slot (tt+3)&3 == (tt-1)&3 was drained at iter tt-1's lgkmcnt(0)+barrier.
  for (int tt = 0; tt < NT - 3; ++tt) {
    PH_A(tt, STAGE_A(tt + 3));
    PH_B(tt, STAGE_B(tt + 3), VMW(8));
  }
  PH_A(NT - 3, NOOP); PH_B(NT - 3, NOOP, VMW(4));
  PH_A(NT - 2, NOOP); PH_B(NT - 2, NOOP, VMW(0));
  PH_A(NT - 1, NOOP); PH_B(NT - 1, NOOP, NOOP);

  #undef STAGE_A
  #undef STAGE_B
  #undef PH_A
  #undef PH_B

  // epilogue: C/D layout col = lane&15, row = (lane>>4)*4 + j
  #pragma unroll
  for (int n = 0; n < 4; ++n) {
    const int col = bcol + wc * 64 + n * 16 + fr;
    const float bv = bias[col];
    #pragma unroll
    for (int m = 0; m < 8; ++m) {
      const int rowb = brow + wr * 128 + m * 16 + fq * 4;
      #pragma unroll
      for (int j = 0; j < 4; ++j)
        out[(size_t)(rowb + j) * N_DIM + col] = acc[m][n][j] + bv;
    }
  }
}

// ---- fallback (ws too small): fused dequant 128^2 tile, correct but slower ----
__global__ __launch_bounds__(256) void gemm_fallback_kernel(
    const float* __restrict__ x, const int* __restrict__ qw,
    const float* __restrict__ scale, const float* __restrict__ zp,
    const float* __restrict__ bias, float* __restrict__ out) {
  __shared__ unsigned short lds_a[128 * 32];
  __shared__ unsigned short lds_b[128 * 32];
  const int t = threadIdx.x;
  const int lane = t & 63;
  const int wid = t >> 6;
  const int wr = wid >> 1, wc = wid & 1;
  const int fr = lane & 15, fq = lane >> 4;
  const int nwg = gridDim.x;
  const int cpx = nwg >> 3;
  const int bid = blockIdx.x;
  const int swz = (bid & 7) * cpx + (bid >> 3);
  const int bx = swz & 31, by = swz >> 5;
  const int brow = by * 128, bcol = bx * 128;
  const int r0 = t >> 2, c8 = (t & 3) * 8;
  f32x4 acc[4][4] = {};
  const float ss = scale[0], zs = zp[0];
  for (int kk = 0; kk < K_DIM; kk += 32) {
    ushort8 ua[2], ub[2];
    #pragma unroll
    for (int i = 0; i < 2; ++i) {
      const float* gp = x + (size_t)(brow + i * 64 + r0) * K_DIM + kk + c8;
      float4 v0 = *(const float4*)gp;
      float4 v1 = *(const float4*)(gp + 4);
      ua[i][0] = f2bf(v0.x); ua[i][1] = f2bf(v0.y); ua[i][2] = f2bf(v0.z); ua[i][3] = f2bf(v0.w);
      ua[i][4] = f2bf(v1.x); ua[i][5] = f2bf(v1.y); ua[i][6] = f2bf(v1.z); ua[i][7] = f2bf(v1.w);
      const int* qp = qw + (size_t)(bcol + i * 64 + r0) * K_DIM + kk + c8;
      int4 q0 = *(const int4*)qp;
      int4 q1 = *(const int4*)(qp + 4);
      ub[i][0] = f2bf(ss * ((float)q0.x - zs)); ub[i][1] = f2bf(ss * ((float)q0.y - zs));
      ub[i][2] = f2bf(ss * ((float)q0.z - zs)); ub[i][3] = f2bf(ss * ((float)q0.w - zs));
      ub[i][4] = f2bf(ss * ((float)q1.x - zs)); ub[i][5] = f2bf(ss * ((float)q1.y - zs));
      ub[i][6] = f2bf(ss * ((float)q1.z - zs)); ub[i][7] = f2bf(ss * ((float)q1.w - zs));
    }
    __syncthreads();
    #pragma unroll
    for (int i = 0; i < 2; ++i) {
      *(ushort8*)(lds_a + ((size_t)i * 256 + t) * 8) = ua[i];
      *(ushort8*)(lds_b + ((size_t)i * 256 + t) * 8) = ub[i];
    }
    __syncthreads();
    bf16x8 af[4], bfr[4];
    #pragma unroll
    for (int m = 0; m < 4; ++m)
      af[m] = *(const bf16x8*)(lds_a + (wr * 64 + m * 16 + fr) * 32 + fq * 8);
    #pragma unroll
    for (int n = 0; n < 4; ++n)
      bfr[n] = *(const bf16x8*)(lds_b + (wc * 64 + n * 16 + fr) * 32 + fq * 8);
    #pragma unroll
    for (int m = 0; m < 4; ++m)
      #pragma unroll
      for (int n = 0; n < 4; ++n)
        acc[m][n] = __builtin_amdgcn_mfma_f32_16x16x32_bf16(af[m], bfr[n], acc[m][n], 0, 0, 0);
  }
  #pragma unroll
  for (int n = 0; n < 4; ++n) {
    const int col = bcol + wc * 64 + n * 16 + fr;
    const float bv = bias[col];
    #pragma unroll
    for (int m = 0; m < 4; ++m) {
      const int rowb = brow + wr * 64 + m * 16 + fq * 4;
      #pragma unroll
      for (int j = 0; j < 4; ++j)
        out[(size_t)(rowb + j) * N_DIM + col] = acc[m][n][j] + bv;
    }
  }
}

extern "C" void kernel_launch(void* const* d_in, const int* in_sizes, int n_in,
                              void* d_out, int out_size, void* d_ws, size_t ws_size,
                              hipStream_t stream) {
  const float* x = (const float*)d_in[0];
  const int* qw = (const int*)d_in[1];
  const float* scale = (const float*)d_in[2];
  const float* zp = (const float*)d_in[3];
  const float* bias = (const float*)d_in[4];
  float* out = (float*)d_out;

  const size_t xb_bytes = (size_t)M_DIM * K_DIM * 2;
  const size_t wb_bytes = (size_t)N_DIM * K_DIM * 2;

  if (ws_size >= xb_bytes + wb_bytes) {
    unsigned short* xbuf = (unsigned short*)d_ws;
    unsigned short* wbuf = (unsigned short*)((char*)d_ws + xb_bytes);
    cvt_x_kernel<<<2048, 256, 0, stream>>>(x, xbuf, (long long)M_DIM * K_DIM / 8);
    dequant_w_kernel<<<2048, 256, 0, stream>>>(qw, scale, zp, wbuf, (long long)N_DIM * K_DIM / 8);
    const int grid = (M_DIM / 256) * (N_DIM / 256);  // 512, divisible by 8
    gemm256_kernel<<<grid, 512, 0, stream>>>(xbuf, wbuf, bias, out);
  } else {
    const int grid = (M_DIM / 128) * (N_DIM / 128);  // 2048
    gemm_fallback_kernel<<<grid, 256, 0, stream>>>(x, qw, scale, zp, bias, out);
  }
}